// Round 10
// baseline (318.311 us; speedup 1.0000x reference)
//
#include <hip/hip_runtime.h>
#include <hip/hip_bf16.h>

// NTM cell forward: T=512, B=32, D=1024, N=128. All I/O f32.
// R19: GEMM side reverted to R17 exactly (gemm5 + knorm; R18's fusion
// regressed both gemm and the scan's L2 pre-touch). Scan-v2: one S-row
// per 64-lane wave (2 f32/lane, was 4 over 32 lanes) -> 4096 waves =
// 4 waves/SIMD (was 2). Issue work per element conserved; the extra
// occupancy covers the tanh/dpp dependency chains (R17: 622 cyc/t at
// VALUBusy 65% with per-wave issue 202 -> idle = uncovered chains).
// Reduce gains one DPP stage (row_bcast31) -> full-64 sum in lane 63.
// ws: C (41,943,040) | W2 (1,310,720) | S_mid (8,388,608).

typedef __attribute__((ext_vector_type(8))) short bf16x8;
typedef __attribute__((ext_vector_type(4))) float f32x4;
typedef __attribute__((ext_vector_type(2))) float f32x2;
typedef __attribute__((ext_vector_type(4))) unsigned short u16x4;
typedef __attribute__((ext_vector_type(8))) unsigned short u16x8;

static constexpr int T_STEPS = 512;
static constexpr int BATCH   = 32;
static constexpr int DDIM    = 1024;
static constexpr int NDIM    = 128;
static constexpr int LDC     = 5 * NDIM;         // 640
static constexpr int MROWS   = T_STEPS * BATCH;  // 16384
static constexpr int OUT_N   = T_STEPS * BATCH * NDIM;  // 2,097,152

static constexpr size_t C_BYTES  = (size_t)MROWS * LDC * 4;   // 41,943,040
static constexpr size_t W2_BYTES = 5ull * NDIM * DDIM * 2;    // 1,310,720

// round-to-nearest-even f32 -> bf16
__device__ __forceinline__ unsigned short rne_bf16(float v) {
    unsigned u = __builtin_bit_cast(unsigned, v);
    u += 0x7FFFu + ((u >> 16) & 1u);
    return (unsigned short)(u >> 16);
}

// ---------------- Phase 0: W f32 -> frag-swizzled bf16 ----------------
__global__ __launch_bounds__(256) void wconv_kernel(
    const float* __restrict__ w0, const float* __restrict__ w1,
    const float* __restrict__ w2, const float* __restrict__ w3,
    const float* __restrict__ w4,
    unsigned short* __restrict__ W2)
{
    const int idx = blockIdx.x * 256 + threadIdx.x;   // f32x4 index, 163840 total
    const size_t e = (size_t)idx * 4;
    const int bn = (int)(e >> 17);                    // 131,072 elems per weight
    const int r  = (int)(e & 131071);
    const int n  = r >> 10;
    const int k  = r & 1023;

    const float* wp = w0;
    if (bn == 1) wp = w1;
    else if (bn == 2) wp = w2;
    else if (bn == 3) wp = w3;
    else if (bn == 4) wp = w4;

    f32x4 v = *(const f32x4*)(wp + r);
    u16x4 h;
#pragma unroll
    for (int j = 0; j < 4; ++j) h[j] = rne_bf16(v[j]);

    const int kk   = k >> 5;
    const int quad = (k >> 3) & 3;
    const size_t off = ((((size_t)(bn * 32 + kk) * 128 + n) * 4 + quad) * 8) + (k & 7);
    *(u16x4*)(W2 + off) = h;
}

// ---------------- Phase 1: A-resident GEMM, bn-pass structure ----------------
template<int BN0, int NB>
__device__ __forceinline__ void gemm_pass(
    const unsigned short (&lds)[64 * 1024],
    const unsigned short* __restrict__ bp,
    float* __restrict__ C,
    int m0, int wave, int quad, int l16, int aswz)
{
    auto LDA = [&](int mi, int kk) -> bf16x8 {
        const int byteo = (mi * 16 + l16) * 2048 + ((kk * 64 + quad * 16) ^ aswz);
        return *(const bf16x8*)((const char*)lds + byteo);
    };

    f32x4 acc[NB][4];
#pragma unroll
    for (int q = 0; q < NB; ++q)
#pragma unroll
        for (int mi = 0; mi < 4; ++mi) acc[q][mi] = (f32x4)(0.0f);

    const unsigned short* bpp[NB];
#pragma unroll
    for (int q = 0; q < NB; ++q) bpp[q] = bp + (size_t)(BN0 + q) * 131072;

    bf16x8 aC[4], bC[NB], aN[4], bN[NB];
#pragma unroll
    for (int mi = 0; mi < 4; ++mi) aC[mi] = LDA(mi, 0);
#pragma unroll
    for (int q = 0; q < NB; ++q) bC[q] = *(const bf16x8*)bpp[q];

    for (int kk = 0; kk < 32; kk += 2) {
        // prefetch kk+1
#pragma unroll
        for (int mi = 0; mi < 4; ++mi) aN[mi] = LDA(mi, kk + 1);
#pragma unroll
        for (int q = 0; q < NB; ++q)
            bN[q] = *(const bf16x8*)(bpp[q] + (size_t)(kk + 1) * 4096);
        // compute kk
#pragma unroll
        for (int q = 0; q < NB; ++q)
#pragma unroll
            for (int mi = 0; mi < 4; ++mi)
                acc[q][mi] = __builtin_amdgcn_mfma_f32_16x16x32_bf16(
                    aC[mi], bC[q], acc[q][mi], 0, 0, 0);
        // prefetch kk+2
        if (kk < 30) {
#pragma unroll
            for (int mi = 0; mi < 4; ++mi) aC[mi] = LDA(mi, kk + 2);
#pragma unroll
            for (int q = 0; q < NB; ++q)
                bC[q] = *(const bf16x8*)(bpp[q] + (size_t)(kk + 2) * 4096);
        }
        // compute kk+1
#pragma unroll
        for (int q = 0; q < NB; ++q)
#pragma unroll
            for (int mi = 0; mi < 4; ++mi)
                acc[q][mi] = __builtin_amdgcn_mfma_f32_16x16x32_bf16(
                    aN[mi], bN[q], acc[q][mi], 0, 0, 0);
    }

    // per-pass epilogue (overlaps next pass's loads)
#pragma unroll
    for (int q = 0; q < NB; ++q)
#pragma unroll
        for (int mi = 0; mi < 4; ++mi) {
            const int rw = m0 + mi * 16 + quad * 4;
            const int cl = (BN0 + q) * 128 + wave * 16 + l16;
#pragma unroll
            for (int r = 0; r < 4; ++r)
                C[(size_t)(rw + r) * LDC + cl] = acc[q][mi][r];
        }
}

// 256 blocks, 512 threads (8 waves), 1 block/CU (128 KiB LDS).
__global__ __launch_bounds__(512, 2) void gemm5_kernel(
    const float* __restrict__ x,
    const unsigned short* __restrict__ W2,
    float* __restrict__ C)
{
    __shared__ unsigned short lds[64 * 1024];  // 131,072 B

    const int m0   = blockIdx.x * 64;
    const int tid  = threadIdx.x;
    const int wave = tid >> 6, lane = tid & 63;
    const int quad = lane >> 4, l16 = lane & 15;

    // ---- stage: coalesced 32 B/thread/iter, swizzled 16 B LDS writes ----
    {
        const int k8 = tid & 127;       // 8-elem k-group 0..127
        const int rb = tid >> 7;        // 0..3
#pragma unroll 4
        for (int it = 0; it < 16; ++it) {
            const int row = it * 4 + rb;
            const float* src = x + (size_t)(m0 + row) * DDIM + k8 * 8;
            f32x4 v0 = *(const f32x4*)src;
            f32x4 v1 = *(const f32x4*)(src + 4);
            u16x8 h;
            h[0] = rne_bf16(v0[0]); h[1] = rne_bf16(v0[1]);
            h[2] = rne_bf16(v0[2]); h[3] = rne_bf16(v0[3]);
            h[4] = rne_bf16(v1[0]); h[5] = rne_bf16(v1[1]);
            h[6] = rne_bf16(v1[2]); h[7] = rne_bf16(v1[3]);
            const int byteo = row * 2048 + ((k8 * 16) ^ ((row & 7) << 4));
            *(u16x8*)((char*)lds + byteo) = h;
        }
    }
    __syncthreads();

    const int aswz = (l16 & 7) << 4;
    const unsigned short* bp = W2 + ((size_t)((wave * 16 + l16) * 4 + quad)) * 8;

    gemm_pass<0, 2>(lds, bp, C, m0, wave, quad, l16, aswz);
    gemm_pass<2, 2>(lds, bp, C, m0, wave, quad, l16, aswz);
    gemm_pass<4, 1>(lds, bp, C, m0, wave, quad, l16, aswz);
}

// ---------------- knorm prep ----------------
__global__ __launch_bounds__(256) void knorm_kernel(float* __restrict__ C)
{
    const int r    = blockIdx.x * 4 + (threadIdx.x >> 6);
    const int lane = threadIdx.x & 63;
    float* base = C + (size_t)r * LDC;

    f32x2 k2 = *(const f32x2*)(base + lane * 2);
    f32x2 v2 = *(const f32x2*)(base + NDIM + lane * 2);
    f32x2 w2 = *(const f32x2*)(base + 4 * NDIM + lane * 2);

    float ss = k2.x * k2.x + k2.y * k2.y;
#pragma unroll
    for (int off = 32; off >= 1; off >>= 1) ss += __shfl_xor(ss, off, 64);
    float inv = __builtin_amdgcn_rcpf(sqrtf(ss) + 1e-6f);

    f32x2 kn = {k2.x * inv, k2.y * inv};
    f32x2 wv = {v2.x * w2.x, v2.y * w2.y};
    *(f32x2*)(base + lane * 2) = kn;
    *(f32x2*)(base + NDIM + lane * 2) = wv;
}

// ---------------- recurrent scan ----------------
__device__ __forceinline__ float tanh_fast(float xx) {
    float ex = __builtin_amdgcn_exp2f(xx * 2.8853900817779268f);  // e^(2x)
    float r  = __builtin_amdgcn_rcpf(ex + 1.0f);
    return fmaf(-2.0f, r, 1.0f);
}

template <int CTRL, int RMASK>
__device__ __forceinline__ float dpp_add(float x) {
    int yi = __builtin_amdgcn_update_dpp(
        0, __builtin_bit_cast(int, x), CTRL, RMASK, 0xF, true);
    return x + __builtin_bit_cast(float, yi);
}

// Full 64-lane sum; valid in lanes 48..63 (store from lane 63).
__device__ __forceinline__ float dpp_reduce64(float x) {
    x = dpp_add<0xB1,  0xF>(x);  // + lane^1
    x = dpp_add<0x4E,  0xF>(x);  // + lane^2
    x = dpp_add<0x141, 0xF>(x);  // row_half_mirror: + lane^4
    x = dpp_add<0x140, 0xF>(x);  // row_mirror: + lane^8
    x = dpp_add<0x142, 0xA>(x);  // row_bcast15: rows 1,3 += row 0,2 sum
    x = dpp_add<0x143, 0xC>(x);  // row_bcast31: rows 2,3 += lanes0..31 sum
    return x;
}

// Scan-v2: one S-row per 64-lane wave, 2 f32/lane. Grid 1024 x 256
// (4 waves/block) = 4096 waves = 4 waves/SIMD. NOUTER unrolled-4 outer
// iters from t0; Sin -> Sout; TAIL adds the clamped peeled iteration.
template<int NOUTER, bool TAIL>
__global__ __launch_bounds__(256, 4) void ntm_scan2(
    const float* __restrict__ C, const float* __restrict__ Sin,
    float* __restrict__ Sout, float* __restrict__ out, int t0)
{
    const int L    = blockIdx.x;            // 0..1023
    const int b    = (L & 7) + 8 * ((L >> 3) & 3);
    const int row  = (L >> 5) * 4 + (threadIdx.x >> 6);
    const int lane = threadIdx.x & 63;
    const int col0 = lane * 2;

    f32x2 S = *(const f32x2*)(Sin + ((size_t)b * NDIM + row) * NDIM + col0);

    const size_t STRIDE = (size_t)BATCH * LDC;
    const float* pb = C + (size_t)b * LDC;
    const float* p0 = pb + (size_t)t0 * STRIDE;

    f32x2 kS[4], qS[4];
    float eS[4], wvS[4];

#pragma unroll
    for (int s = 0; s < 2; ++s) {
        const float* p = p0 + (size_t)s * STRIDE;
        kS[s]  = *(const f32x2*)(p + col0);
        qS[s]  = *(const f32x2*)(p + 2 * NDIM + col0);
        eS[s]  = p[3 * NDIM + row];
        wvS[s] = p[NDIM + row];
    }

    float* opc = out + (size_t)t0 * BATCH * NDIM + (size_t)b * NDIM + row;
    const float* pc = p0 + 2 * STRIDE;           // prefetch cursor (t+2)

    for (int ti = 0; ti < NOUTER; ++ti) {
#pragma unroll
        for (int j = 0; j < 4; ++j) {
            const int ps = (j + 2) & 3;
            kS[ps]  = *(const f32x2*)(pc + col0);
            qS[ps]  = *(const f32x2*)(pc + 2 * NDIM + col0);
            eS[ps]  = pc[3 * NDIM + row];
            wvS[ps] = pc[NDIM + row];
            pc += STRIDE;

            float dot = 0.0f;
#pragma unroll
            for (int u = 0; u < 2; ++u) {
                float t0v = fmaf(-eS[j], S[u], wvS[j]);
                float pre = fmaf(kS[j][u], t0v, S[u]);
                S[u] = tanh_fast(pre);
                dot = fmaf(S[u], qS[j][u], dot);
            }
            dot = dpp_reduce64(dot);

            if (lane == 63)
                *opc = dot;  // raw; silu in epilogue
            opc += BATCH * NDIM;
        }
    }

    if (TAIL) {
        // peeled final outer iteration, prefetch clamped to T-1
#pragma unroll
        for (int j = 0; j < 4; ++j) {
            const int ps = (j + 2) & 3;
            int tp = t0 + NOUTER * 4 + 2 + j;
            if (tp > T_STEPS - 1) tp = T_STEPS - 1;
            const float* p = pb + (size_t)tp * STRIDE;
            kS[ps]  = *(const f32x2*)(p + col0);
            qS[ps]  = *(const f32x2*)(p + 2 * NDIM + col0);
            eS[ps]  = p[3 * NDIM + row];
            wvS[ps] = p[NDIM + row];

            float dot = 0.0f;
#pragma unroll
            for (int u = 0; u < 2; ++u) {
                float t0v = fmaf(-eS[j], S[u], wvS[j]);
                float pre = fmaf(kS[j][u], t0v, S[u]);
                S[u] = tanh_fast(pre);
                dot = fmaf(S[u], qS[j][u], dot);
            }
            dot = dpp_reduce64(dot);

            if (lane == 63)
                *opc = dot;
            opc += BATCH * NDIM;
        }
    }

    *(f32x2*)(Sout + ((size_t)b * NDIM + row) * NDIM + col0) = S;
}

// ---------------- silu epilogue: y = d^2 * sigmoid(d) over out[0:OUT_N] ----
__global__ __launch_bounds__(256) void silu_kernel(float* __restrict__ out)
{
    const int i = blockIdx.x * 256 + threadIdx.x;  // f32x4 index
    f32x4 d = ((const f32x4*)out)[i];
    f32x4 y;
#pragma unroll
    for (int j = 0; j < 4; ++j) {
        float sg = __builtin_amdgcn_rcpf(
            1.0f + __builtin_amdgcn_exp2f(-d[j] * 1.4426950408889634f));
        y[j] = d[j] * d[j] * sg;
    }
    ((f32x4*)out)[i] = y;
}

extern "C" void kernel_launch(void* const* d_in, const int* in_sizes, int n_in,
                              void* d_out, int out_size, void* d_ws, size_t ws_size,
                              hipStream_t stream) {
    const float* x  = (const float*)d_in[0];
    const float* S0 = (const float*)d_in[1];
    const float* wk = (const float*)d_in[2];
    const float* wv = (const float*)d_in[3];
    const float* wq = (const float*)d_in[4];
    const float* we = (const float*)d_in[5];
    const float* ww = (const float*)d_in[6];
    float* out = (float*)d_out;
    float* C   = (float*)d_ws;
    unsigned short* W2 = (unsigned short*)((char*)d_ws + C_BYTES);
    float* S_mid = (float*)((char*)d_ws + C_BYTES + W2_BYTES);

    wconv_kernel<<<640, 256, 0, stream>>>(wk, wv, wq, we, ww, W2);
    gemm5_kernel<<<256, 512, 0, stream>>>(x, W2, C);
    knorm_kernel<<<MROWS / 4, 256, 0, stream>>>(C);
    // t 0..255 (prefetch reaches t=257, valid), S0 -> S_mid
    ntm_scan2<64, false><<<1024, 256, 0, stream>>>(C, S0, S_mid, out, 0);
    // t 256..507 main + 508..511 clamped tail, S_mid -> final S in out
    ntm_scan2<63, true><<<1024, 256, 0, stream>>>(
        C, S_mid, out + (size_t)OUT_N, out, 256);
    silu_kernel<<<OUT_N / 1024, 256, 0, stream>>>(out);
}

// Round 11
// 270.012 us; speedup vs baseline: 1.1789x; 1.1789x over previous
//
#include <hip/hip_runtime.h>
#include <hip/hip_bf16.h>

// NTM cell forward: T=512, B=32, D=1024, N=128. All I/O f32.
// R20: kernel-count reduction with measured parts. R19 falsified the
// scan occupancy theory (4 waves/SIMD = +50% issue, 98us/part): the
// R14 scan body is a tested local optimum -- restored verbatim, unsplit.
// R17 established ~10us/kernel launch overhead -> fuse knorm into the
// GEMM using R18's verified epilogue (passed; its regression was the
// B-ring clamps + scan L2 effect, not the fusion) on gemm5's exact
// depth-1 kk-loop. 4 kernels: wconv, gemm7, scan, silu.
// ws: C (41,943,040) | W2 (1,310,720).

typedef __attribute__((ext_vector_type(8))) short bf16x8;
typedef __attribute__((ext_vector_type(4))) float f32x4;
typedef __attribute__((ext_vector_type(2))) float f32x2;
typedef __attribute__((ext_vector_type(4))) unsigned short u16x4;
typedef __attribute__((ext_vector_type(8))) unsigned short u16x8;

static constexpr int T_STEPS = 512;
static constexpr int BATCH   = 32;
static constexpr int DDIM    = 1024;
static constexpr int NDIM    = 128;
static constexpr int LDC     = 5 * NDIM;         // 640
static constexpr int MROWS   = T_STEPS * BATCH;  // 16384
static constexpr int OUT_N   = T_STEPS * BATCH * NDIM;  // 2,097,152

static constexpr size_t C_BYTES  = (size_t)MROWS * LDC * 4;   // 41,943,040

// round-to-nearest-even f32 -> bf16
__device__ __forceinline__ unsigned short rne_bf16(float v) {
    unsigned u = __builtin_bit_cast(unsigned, v);
    u += 0x7FFFu + ((u >> 16) & 1u);
    return (unsigned short)(u >> 16);
}

// ---------------- Phase 0: W f32 -> frag-swizzled bf16 ----------------
__global__ __launch_bounds__(256) void wconv_kernel(
    const float* __restrict__ w0, const float* __restrict__ w1,
    const float* __restrict__ w2, const float* __restrict__ w3,
    const float* __restrict__ w4,
    unsigned short* __restrict__ W2)
{
    const int idx = blockIdx.x * 256 + threadIdx.x;   // f32x4 index, 163840 total
    const size_t e = (size_t)idx * 4;
    const int bn = (int)(e >> 17);                    // 131,072 elems per weight
    const int r  = (int)(e & 131071);
    const int n  = r >> 10;
    const int k  = r & 1023;

    const float* wp = w0;
    if (bn == 1) wp = w1;
    else if (bn == 2) wp = w2;
    else if (bn == 3) wp = w3;
    else if (bn == 4) wp = w4;

    f32x4 v = *(const f32x4*)(wp + r);
    u16x4 h;
#pragma unroll
    for (int j = 0; j < 4; ++j) h[j] = rne_bf16(v[j]);

    const int kk   = k >> 5;
    const int quad = (k >> 3) & 3;
    const size_t off = ((((size_t)(bn * 32 + kk) * 128 + n) * 4 + quad) * 8) + (k & 7);
    *(u16x4*)(W2 + off) = h;
}

// ---------------- Phase 1: A-resident GEMM + fused knorm epilogue -----------
// gemm5's depth-1 double-buffered kk-loop, NO clamps (verbatim from R17).
template<int NB>
__device__ __forceinline__ void kloop(
    const unsigned short* __restrict__ lds,
    const unsigned short* const (&bpp)[NB],
    int l16, int quad, int aswz,
    f32x4 (&acc)[NB][4])
{
    auto LDA = [&](int mi, int kk) -> bf16x8 {
        const int byteo = (mi * 16 + l16) * 2048 + ((kk * 64 + quad * 16) ^ aswz);
        return *(const bf16x8*)((const char*)lds + byteo);
    };

#pragma unroll
    for (int q = 0; q < NB; ++q)
#pragma unroll
        for (int mi = 0; mi < 4; ++mi) acc[q][mi] = (f32x4)(0.0f);

    bf16x8 aC[4], bC[NB], aN[4], bN[NB];
#pragma unroll
    for (int mi = 0; mi < 4; ++mi) aC[mi] = LDA(mi, 0);
#pragma unroll
    for (int q = 0; q < NB; ++q) bC[q] = *(const bf16x8*)bpp[q];

    for (int kk = 0; kk < 32; kk += 2) {
        // prefetch kk+1
#pragma unroll
        for (int mi = 0; mi < 4; ++mi) aN[mi] = LDA(mi, kk + 1);
#pragma unroll
        for (int q = 0; q < NB; ++q)
            bN[q] = *(const bf16x8*)(bpp[q] + (size_t)(kk + 1) * 4096);
        // compute kk
#pragma unroll
        for (int q = 0; q < NB; ++q)
#pragma unroll
            for (int mi = 0; mi < 4; ++mi)
                acc[q][mi] = __builtin_amdgcn_mfma_f32_16x16x32_bf16(
                    aC[mi], bC[q], acc[q][mi], 0, 0, 0);
        // prefetch kk+2
        if (kk < 30) {
#pragma unroll
            for (int mi = 0; mi < 4; ++mi) aC[mi] = LDA(mi, kk + 2);
#pragma unroll
            for (int q = 0; q < NB; ++q)
                bC[q] = *(const bf16x8*)(bpp[q] + (size_t)(kk + 2) * 4096);
        }
        // compute kk+1
#pragma unroll
        for (int q = 0; q < NB; ++q)
#pragma unroll
            for (int mi = 0; mi < 4; ++mi)
                acc[q][mi] = __builtin_amdgcn_mfma_f32_16x16x32_bf16(
                    aN[mi], bN[q], acc[q][mi], 0, 0, 0);
    }
}

// 256 blocks, 512 threads (8 waves), 1 block/CU (130 KiB LDS).
// Pass order {v,w} -> {k,q}+norm -> {e}; writes kn/wv/q/e, skips bn4.
__global__ __launch_bounds__(512, 2) void gemm7_kernel(
    const float* __restrict__ x,
    const unsigned short* __restrict__ W2,
    float* __restrict__ C)
{
    __shared__ unsigned short lds[64 * 1024 + 1024];  // A tile (128K) + reduce (2K)

    const int m0   = blockIdx.x * 64;
    const int tid  = threadIdx.x;
    const int wave = tid >> 6, lane = tid & 63;
    const int quad = lane >> 4, l16 = lane & 15;

    // ---- stage: coalesced 32 B/thread/iter, swizzled 16 B LDS writes ----
    {
        const int k8 = tid & 127;       // 8-elem k-group 0..127
        const int rb = tid >> 7;        // 0..3
#pragma unroll 4
        for (int it = 0; it < 16; ++it) {
            const int row = it * 4 + rb;
            const float* src = x + (size_t)(m0 + row) * DDIM + k8 * 8;
            f32x4 v0 = *(const f32x4*)src;
            f32x4 v1 = *(const f32x4*)(src + 4);
            u16x8 h;
            h[0] = rne_bf16(v0[0]); h[1] = rne_bf16(v0[1]);
            h[2] = rne_bf16(v0[2]); h[3] = rne_bf16(v0[3]);
            h[4] = rne_bf16(v1[0]); h[5] = rne_bf16(v1[1]);
            h[6] = rne_bf16(v1[2]); h[7] = rne_bf16(v1[3]);
            const int byteo = row * 2048 + ((k8 * 16) ^ ((row & 7) << 4));
            *(u16x8*)((char*)lds + byteo) = h;
        }
    }
    __syncthreads();

    const int aswz = (l16 & 7) << 4;
    const unsigned short* bp = W2 + ((size_t)((wave * 16 + l16) * 4 + quad)) * 8;
    float* lds2f = (float*)((char*)lds + 131072);  // [row 0..63][wave 0..7]

    auto STORE = [&](int bn, const f32x4 (&a)[4]) {
#pragma unroll
        for (int mi = 0; mi < 4; ++mi) {
            const int rw = m0 + mi * 16 + quad * 4;
            const int cl = bn * 128 + wave * 16 + l16;
#pragma unroll
            for (int r = 0; r < 4; ++r)
                C[(size_t)(rw + r) * LDC + cl] = a[mi][r];
        }
    };

    // ---- pass 1: v (bn1) & w (bn4) -> wv ----
    f32x4 wv[4];
    {
        const unsigned short* bppVW[2] = { bp + 1 * 131072, bp + 4 * 131072 };
        f32x4 acc[2][4];
        kloop<2>(lds, bppVW, l16, quad, aswz, acc);
#pragma unroll
        for (int mi = 0; mi < 4; ++mi)
#pragma unroll
            for (int r = 0; r < 4; ++r)
                wv[mi][r] = acc[0][mi][r] * acc[1][mi][r];
    }

    // ---- pass 2: k (bn0) & q (bn2); fused row-norm on k ----
    {
        const unsigned short* bppKQ[2] = { bp, bp + 2 * 131072 };
        f32x4 acc[2][4];
        kloop<2>(lds, bppKQ, l16, quad, aswz, acc);

        // per-(mi,r) partial: sum of k^2 over this wave's 16 cols
#pragma unroll
        for (int mi = 0; mi < 4; ++mi)
#pragma unroll
            for (int r = 0; r < 4; ++r) {
                float s = acc[0][mi][r] * acc[0][mi][r];
                s += __shfl_xor(s, 1);
                s += __shfl_xor(s, 2);
                s += __shfl_xor(s, 4);
                s += __shfl_xor(s, 8);
                if (l16 == 0)
                    lds2f[(mi * 16 + quad * 4 + r) * 8 + wave] = s;
            }
        __syncthreads();

        // total over 8 waves, then scale k rows
#pragma unroll
        for (int mi = 0; mi < 4; ++mi)
#pragma unroll
            for (int r = 0; r < 4; ++r) {
                const int row = mi * 16 + quad * 4 + r;
                f32x4 p0 = *(const f32x4*)&lds2f[row * 8];
                f32x4 p1 = *(const f32x4*)&lds2f[row * 8 + 4];
                float ss = (p0[0] + p0[1]) + (p0[2] + p0[3])
                         + (p1[0] + p1[1]) + (p1[2] + p1[3]);
                float inv = __builtin_amdgcn_rcpf(sqrtf(ss) + 1e-6f);
                acc[0][mi][r] *= inv;
            }

        STORE(0, acc[0]);  // kn
        STORE(1, wv);      // w*v
        STORE(2, acc[1]);  // q
    }

    // ---- pass 3: e (bn3) ----
    {
        const unsigned short* bppE[1] = { bp + 3 * 131072 };
        f32x4 acc[1][4];
        kloop<1>(lds, bppE, l16, quad, aswz, acc);
        STORE(3, acc[0]);  // e  (bn4 never written; nothing reads it)
    }
}

// ---------------- recurrent scan (R14-verbatim, unsplit) ----------------
__device__ __forceinline__ float tanh_fast(float xx) {
    float ex = __builtin_amdgcn_exp2f(xx * 2.8853900817779268f);  // e^(2x)
    float r  = __builtin_amdgcn_rcpf(ex + 1.0f);
    return fmaf(-2.0f, r, 1.0f);
}

template <int CTRL, int RMASK>
__device__ __forceinline__ float dpp_add(float x) {
    int yi = __builtin_amdgcn_update_dpp(
        0, __builtin_bit_cast(int, x), CTRL, RMASK, 0xF, true);
    return x + __builtin_bit_cast(float, yi);
}

// Sum across each 32-lane group; valid in lanes 16..31 / 48..63.
__device__ __forceinline__ float dpp_reduce32(float x) {
    x = dpp_add<0xB1,  0xF>(x);  // + lane^1
    x = dpp_add<0x4E,  0xF>(x);  // + lane^2
    x = dpp_add<0x141, 0xF>(x);  // row_half_mirror: + lane^4
    x = dpp_add<0x140, 0xF>(x);  // row_mirror: + lane^8
    x = dpp_add<0x142, 0xA>(x);  // row_bcast15: rows 1,3 += row 0,2 sum
    return x;
}

// Grid 512 x 256; 32-lane group per S-row, 4 f32/lane, 2 rows/wave.
__global__ __launch_bounds__(256, 2) void ntm_scan_kernel(
    const float* __restrict__ C, const float* __restrict__ S0,
    float* __restrict__ out)
{
    const int L    = blockIdx.x;            // 0..511
    const int b    = (L & 7) + 8 * ((L >> 3) & 3);
    const int row  = (L >> 5) * 8 + (threadIdx.x >> 5);
    const int g    = threadIdx.x & 31;
    const int col0 = g * 4;

    f32x4 S = *(const f32x4*)(S0 + ((size_t)b * NDIM + row) * NDIM + col0);

    const size_t STRIDE = (size_t)BATCH * LDC;
    const float* pb = C + (size_t)b * LDC;

    f32x4 kS[4], qS[4];
    float eS[4], wvS[4];

#pragma unroll
    for (int s = 0; s < 2; ++s) {
        const float* p = pb + (size_t)s * STRIDE;
        kS[s]  = *(const f32x4*)(p + col0);
        qS[s]  = *(const f32x4*)(p + 2 * NDIM + col0);
        eS[s]  = p[3 * NDIM + row];
        wvS[s] = p[NDIM + row];
    }

    float* opc = out + (size_t)b * NDIM + row;   // store cursor
    const float* pc = pb + 2 * STRIDE;           // prefetch cursor (t+2)

    for (int ti = 0; ti < 127; ++ti) {
#pragma unroll
        for (int j = 0; j < 4; ++j) {
            const int ps = (j + 2) & 3;
            kS[ps]  = *(const f32x4*)(pc + col0);
            qS[ps]  = *(const f32x4*)(pc + 2 * NDIM + col0);
            eS[ps]  = pc[3 * NDIM + row];
            wvS[ps] = pc[NDIM + row];
            pc += STRIDE;

            float dot = 0.0f;
#pragma unroll
            for (int u = 0; u < 4; ++u) {
                float t0  = fmaf(-eS[j], S[u], wvS[j]);
                float pre = fmaf(kS[j][u], t0, S[u]);
                S[u] = tanh_fast(pre);
                dot = fmaf(S[u], qS[j][u], dot);
            }
            dot = dpp_reduce32(dot);

            if ((threadIdx.x & 31) == 31)
                *opc = dot;  // raw; silu in epilogue
            opc += BATCH * NDIM;
        }
    }

    // peeled final outer iteration: t = 508..511, prefetch clamped
#pragma unroll
    for (int j = 0; j < 4; ++j) {
        const int ps = (j + 2) & 3;
        int tp = 510 + j;
        if (tp > T_STEPS - 1) tp = T_STEPS - 1;
        const float* p = pb + (size_t)tp * STRIDE;
        kS[ps]  = *(const f32x4*)(p + col0);
        qS[ps]  = *(const f32x4*)(p + 2 * NDIM + col0);
        eS[ps]  = p[3 * NDIM + row];
        wvS[ps] = p[NDIM + row];

        float dot = 0.0f;
#pragma unroll
        for (int u = 0; u < 4; ++u) {
            float t0  = fmaf(-eS[j], S[u], wvS[j]);
            float pre = fmaf(kS[j][u], t0, S[u]);
            S[u] = tanh_fast(pre);
            dot = fmaf(S[u], qS[j][u], dot);
        }
        dot = dpp_reduce32(dot);

        if ((threadIdx.x & 31) == 31)
            *opc = dot;
        opc += BATCH * NDIM;
    }

    *(f32x4*)(out + (size_t)T_STEPS * BATCH * NDIM
              + ((size_t)b * NDIM + row) * NDIM + col0) = S;
}

// ---------------- silu epilogue: y = d^2 * sigmoid(d) over out[0:OUT_N] ----
__global__ __launch_bounds__(256) void silu_kernel(float* __restrict__ out)
{
    const int i = blockIdx.x * 256 + threadIdx.x;  // f32x4 index
    f32x4 d = ((const f32x4*)out)[i];
    f32x4 y;
#pragma unroll
    for (int j = 0; j < 4; ++j) {
        float sg = __builtin_amdgcn_rcpf(
            1.0f + __builtin_amdgcn_exp2f(-d[j] * 1.4426950408889634f));
        y[j] = d[j] * d[j] * sg;
    }
    ((f32x4*)out)[i] = y;
}

extern "C" void kernel_launch(void* const* d_in, const int* in_sizes, int n_in,
                              void* d_out, int out_size, void* d_ws, size_t ws_size,
                              hipStream_t stream) {
    const float* x  = (const float*)d_in[0];
    const float* S0 = (const float*)d_in[1];
    const float* wk = (const float*)d_in[2];
    const float* wv = (const float*)d_in[3];
    const float* wq = (const float*)d_in[4];
    const float* we = (const float*)d_in[5];
    const float* ww = (const float*)d_in[6];
    float* out = (float*)d_out;
    float* C   = (float*)d_ws;
    unsigned short* W2 = (unsigned short*)((char*)d_ws + C_BYTES);

    wconv_kernel<<<640, 256, 0, stream>>>(wk, wv, wq, we, ww, W2);
    gemm7_kernel<<<256, 512, 0, stream>>>(x, W2, C);
    ntm_scan_kernel<<<512, 256, 0, stream>>>(C, S0, out);
    silu_kernel<<<OUT_N / 1024, 256, 0, stream>>>(out);
}

// Round 12
// 269.115 us; speedup vs baseline: 1.1828x; 1.0033x over previous
//
#include <hip/hip_runtime.h>
#include <hip/hip_bf16.h>

// NTM cell forward: T=512, B=32, D=1024, N=128. All I/O f32.
// R21: restore R14's measured-best 5-kernel layout (gemm + knorm
// separate; R20 proved the fusion is -8.5us net). Single change vs R14:
// gemm kloop gets a clamp-free deep pipeline -- B prefetch depth 4,
// A depth 2, named slots (static indexing), steady state kb<=24 (max
// prefetch idx 31, zero guards), peeled tail kb=28. R18's depth-3
// failed on per-load cndmask clamps + reg bloat, not on depth.
// kk order and per-step MFMA order unchanged -> bit-identical output.
// ws: C (41,943,040) | W2 (1,310,720).

typedef __attribute__((ext_vector_type(8))) short bf16x8;
typedef __attribute__((ext_vector_type(4))) float f32x4;
typedef __attribute__((ext_vector_type(2))) float f32x2;
typedef __attribute__((ext_vector_type(4))) unsigned short u16x4;
typedef __attribute__((ext_vector_type(8))) unsigned short u16x8;

static constexpr int T_STEPS = 512;
static constexpr int BATCH   = 32;
static constexpr int DDIM    = 1024;
static constexpr int NDIM    = 128;
static constexpr int LDC     = 5 * NDIM;         // 640
static constexpr int MROWS   = T_STEPS * BATCH;  // 16384
static constexpr int OUT_N   = T_STEPS * BATCH * NDIM;  // 2,097,152

static constexpr size_t C_BYTES = (size_t)MROWS * LDC * 4;  // 41,943,040

// round-to-nearest-even f32 -> bf16
__device__ __forceinline__ unsigned short rne_bf16(float v) {
    unsigned u = __builtin_bit_cast(unsigned, v);
    u += 0x7FFFu + ((u >> 16) & 1u);
    return (unsigned short)(u >> 16);
}

// ---------------- Phase 0: W f32 -> frag-swizzled bf16 ----------------
__global__ __launch_bounds__(256) void wconv_kernel(
    const float* __restrict__ w0, const float* __restrict__ w1,
    const float* __restrict__ w2, const float* __restrict__ w3,
    const float* __restrict__ w4,
    unsigned short* __restrict__ W2)
{
    const int idx = blockIdx.x * 256 + threadIdx.x;   // f32x4 index, 163840 total
    const size_t e = (size_t)idx * 4;
    const int bn = (int)(e >> 17);                    // 131,072 elems per weight
    const int r  = (int)(e & 131071);
    const int n  = r >> 10;
    const int k  = r & 1023;

    const float* wp = w0;
    if (bn == 1) wp = w1;
    else if (bn == 2) wp = w2;
    else if (bn == 3) wp = w3;
    else if (bn == 4) wp = w4;

    f32x4 v = *(const f32x4*)(wp + r);
    u16x4 h;
#pragma unroll
    for (int j = 0; j < 4; ++j) h[j] = rne_bf16(v[j]);

    const int kk   = k >> 5;
    const int quad = (k >> 3) & 3;
    const size_t off = ((((size_t)(bn * 32 + kk) * 128 + n) * 4 + quad) * 8) + (k & 7);
    *(u16x4*)(W2 + off) = h;
}

// ---------------- Phase 1: A-resident GEMM, deep-pipelined kk-loop ----------
template<int BN0, int NB>
__device__ __forceinline__ void gemm_pass(
    const unsigned short (&lds)[64 * 1024],
    const unsigned short* __restrict__ bp,
    float* __restrict__ C,
    int m0, int wave, int quad, int l16, int aswz)
{
    auto LDA = [&](int mi, int kk) -> bf16x8 {
        const int byteo = (mi * 16 + l16) * 2048 + ((kk * 64 + quad * 16) ^ aswz);
        return *(const bf16x8*)((const char*)lds + byteo);
    };

    const unsigned short* bpp[NB];
#pragma unroll
    for (int q = 0; q < NB; ++q) bpp[q] = bp + (size_t)(BN0 + q) * 131072;

    auto LDB = [&](int q, int kk) -> bf16x8 {
        return *(const bf16x8*)(bpp[q] + (size_t)kk * 4096);
    };

    f32x4 acc[NB][4];
#pragma unroll
    for (int q = 0; q < NB; ++q)
#pragma unroll
        for (int mi = 0; mi < 4; ++mi) acc[q][mi] = (f32x4)(0.0f);

    // named slots: aA = even kk, aB = odd kk; b0..b3 = kk mod 4
    bf16x8 aA[4], aB[4], b0[NB], b1[NB], b2[NB], b3[NB];
#pragma unroll
    for (int mi = 0; mi < 4; ++mi) { aA[mi] = LDA(mi, 0); aB[mi] = LDA(mi, 1); }
#pragma unroll
    for (int q = 0; q < NB; ++q) {
        b0[q] = LDB(q, 0); b1[q] = LDB(q, 1);
        b2[q] = LDB(q, 2); b3[q] = LDB(q, 3);
    }

#define MFMA_STEP(AS, BS)                                                    \
    _Pragma("unroll")                                                        \
    for (int q = 0; q < NB; ++q)                                             \
        _Pragma("unroll")                                                    \
        for (int mi = 0; mi < 4; ++mi)                                       \
            acc[q][mi] = __builtin_amdgcn_mfma_f32_16x16x32_bf16(            \
                AS[mi], BS[q], acc[q][mi], 0, 0, 0);

    // steady state: kb = 0,4,...,24; max prefetch index = 24+7 = 31
    for (int kb = 0; kb <= 24; kb += 4) {
        MFMA_STEP(aA, b0)
#pragma unroll
        for (int mi = 0; mi < 4; ++mi) aA[mi] = LDA(mi, kb + 2);
#pragma unroll
        for (int q = 0; q < NB; ++q) b0[q] = LDB(q, kb + 4);

        MFMA_STEP(aB, b1)
#pragma unroll
        for (int mi = 0; mi < 4; ++mi) aB[mi] = LDA(mi, kb + 3);
#pragma unroll
        for (int q = 0; q < NB; ++q) b1[q] = LDB(q, kb + 5);

        MFMA_STEP(aA, b2)
#pragma unroll
        for (int mi = 0; mi < 4; ++mi) aA[mi] = LDA(mi, kb + 4);
#pragma unroll
        for (int q = 0; q < NB; ++q) b2[q] = LDB(q, kb + 6);

        MFMA_STEP(aB, b3)
#pragma unroll
        for (int mi = 0; mi < 4; ++mi) aB[mi] = LDA(mi, kb + 5);
#pragma unroll
        for (int q = 0; q < NB; ++q) b3[q] = LDB(q, kb + 7);
    }

    // tail: kk = 28..31, no prefetch past 31
    MFMA_STEP(aA, b0)
#pragma unroll
    for (int mi = 0; mi < 4; ++mi) aA[mi] = LDA(mi, 30);
    MFMA_STEP(aB, b1)
#pragma unroll
    for (int mi = 0; mi < 4; ++mi) aB[mi] = LDA(mi, 31);
    MFMA_STEP(aA, b2)
    MFMA_STEP(aB, b3)
#undef MFMA_STEP

    // per-pass epilogue (overlaps next pass's loads)
#pragma unroll
    for (int q = 0; q < NB; ++q)
#pragma unroll
        for (int mi = 0; mi < 4; ++mi) {
            const int rw = m0 + mi * 16 + quad * 4;
            const int cl = (BN0 + q) * 128 + wave * 16 + l16;
#pragma unroll
            for (int r = 0; r < 4; ++r)
                C[(size_t)(rw + r) * LDC + cl] = acc[q][mi][r];
        }
}

// 256 blocks, 512 threads (8 waves), 1 block/CU (128 KiB LDS).
__global__ __launch_bounds__(512, 2) void gemm8_kernel(
    const float* __restrict__ x,
    const unsigned short* __restrict__ W2,
    float* __restrict__ C)
{
    __shared__ unsigned short lds[64 * 1024];  // 131,072 B

    const int m0   = blockIdx.x * 64;
    const int tid  = threadIdx.x;
    const int wave = tid >> 6, lane = tid & 63;
    const int quad = lane >> 4, l16 = lane & 15;

    // ---- stage: coalesced 32 B/thread/iter, swizzled 16 B LDS writes ----
    {
        const int k8 = tid & 127;       // 8-elem k-group 0..127
        const int rb = tid >> 7;        // 0..3
#pragma unroll 4
        for (int it = 0; it < 16; ++it) {
            const int row = it * 4 + rb;
            const float* src = x + (size_t)(m0 + row) * DDIM + k8 * 8;
            f32x4 v0 = *(const f32x4*)src;
            f32x4 v1 = *(const f32x4*)(src + 4);
            u16x8 h;
            h[0] = rne_bf16(v0[0]); h[1] = rne_bf16(v0[1]);
            h[2] = rne_bf16(v0[2]); h[3] = rne_bf16(v0[3]);
            h[4] = rne_bf16(v1[0]); h[5] = rne_bf16(v1[1]);
            h[6] = rne_bf16(v1[2]); h[7] = rne_bf16(v1[3]);
            const int byteo = row * 2048 + ((k8 * 16) ^ ((row & 7) << 4));
            *(u16x8*)((char*)lds + byteo) = h;
        }
    }
    __syncthreads();

    const int aswz = (l16 & 7) << 4;
    const unsigned short* bp = W2 + ((size_t)((wave * 16 + l16) * 4 + quad)) * 8;

    gemm_pass<0, 2>(lds, bp, C, m0, wave, quad, l16, aswz);
    gemm_pass<2, 2>(lds, bp, C, m0, wave, quad, l16, aswz);
    gemm_pass<4, 1>(lds, bp, C, m0, wave, quad, l16, aswz);
}

// ---------------- knorm prep ----------------
__global__ __launch_bounds__(256) void knorm_kernel(float* __restrict__ C)
{
    const int r    = blockIdx.x * 4 + (threadIdx.x >> 6);
    const int lane = threadIdx.x & 63;
    float* base = C + (size_t)r * LDC;

    f32x2 k2 = *(const f32x2*)(base + lane * 2);
    f32x2 v2 = *(const f32x2*)(base + NDIM + lane * 2);
    f32x2 w2 = *(const f32x2*)(base + 4 * NDIM + lane * 2);

    float ss = k2.x * k2.x + k2.y * k2.y;
#pragma unroll
    for (int off = 32; off >= 1; off >>= 1) ss += __shfl_xor(ss, off, 64);
    float inv = __builtin_amdgcn_rcpf(sqrtf(ss) + 1e-6f);

    f32x2 kn = {k2.x * inv, k2.y * inv};
    f32x2 wv = {v2.x * w2.x, v2.y * w2.y};
    *(f32x2*)(base + lane * 2) = kn;
    *(f32x2*)(base + NDIM + lane * 2) = wv;
}

// ---------------- recurrent scan (R14-verbatim) ----------------
__device__ __forceinline__ float tanh_fast(float xx) {
    float ex = __builtin_amdgcn_exp2f(xx * 2.8853900817779268f);  // e^(2x)
    float r  = __builtin_amdgcn_rcpf(ex + 1.0f);
    return fmaf(-2.0f, r, 1.0f);
}

template <int CTRL, int RMASK>
__device__ __forceinline__ float dpp_add(float x) {
    int yi = __builtin_amdgcn_update_dpp(
        0, __builtin_bit_cast(int, x), CTRL, RMASK, 0xF, true);
    return x + __builtin_bit_cast(float, yi);
}

// Sum across each 32-lane group; valid in lanes 16..31 / 48..63.
__device__ __forceinline__ float dpp_reduce32(float x) {
    x = dpp_add<0xB1,  0xF>(x);  // + lane^1
    x = dpp_add<0x4E,  0xF>(x);  // + lane^2
    x = dpp_add<0x141, 0xF>(x);  // row_half_mirror: + lane^4
    x = dpp_add<0x140, 0xF>(x);  // row_mirror: + lane^8
    x = dpp_add<0x142, 0xA>(x);  // row_bcast15: rows 1,3 += row 0,2 sum
    return x;
}

// Grid 512 x 256; 32-lane group per S-row, 4 f32/lane, 2 rows/wave.
__global__ __launch_bounds__(256, 2) void ntm_scan_kernel(
    const float* __restrict__ C, const float* __restrict__ S0,
    float* __restrict__ out)
{
    const int L    = blockIdx.x;            // 0..511
    const int b    = (L & 7) + 8 * ((L >> 3) & 3);
    const int row  = (L >> 5) * 8 + (threadIdx.x >> 5);
    const int g    = threadIdx.x & 31;
    const int col0 = g * 4;

    f32x4 S = *(const f32x4*)(S0 + ((size_t)b * NDIM + row) * NDIM + col0);

    const size_t STRIDE = (size_t)BATCH * LDC;
    const float* pb = C + (size_t)b * LDC;

    f32x4 kS[4], qS[4];
    float eS[4], wvS[4];

#pragma unroll
    for (int s = 0; s < 2; ++s) {
        const float* p = pb + (size_t)s * STRIDE;
        kS[s]  = *(const f32x4*)(p + col0);
        qS[s]  = *(const f32x4*)(p + 2 * NDIM + col0);
        eS[s]  = p[3 * NDIM + row];
        wvS[s] = p[NDIM + row];
    }

    float* opc = out + (size_t)b * NDIM + row;   // store cursor
    const float* pc = pb + 2 * STRIDE;           // prefetch cursor (t+2)

    for (int ti = 0; ti < 127; ++ti) {
#pragma unroll
        for (int j = 0; j < 4; ++j) {
            const int ps = (j + 2) & 3;
            kS[ps]  = *(const f32x4*)(pc + col0);
            qS[ps]  = *(const f32x4*)(pc + 2 * NDIM + col0);
            eS[ps]  = pc[3 * NDIM + row];
            wvS[ps] = pc[NDIM + row];
            pc += STRIDE;

            float dot = 0.0f;
#pragma unroll
            for (int u = 0; u < 4; ++u) {
                float t0  = fmaf(-eS[j], S[u], wvS[j]);
                float pre = fmaf(kS[j][u], t0, S[u]);
                S[u] = tanh_fast(pre);
                dot = fmaf(S[u], qS[j][u], dot);
            }
            dot = dpp_reduce32(dot);

            if ((threadIdx.x & 31) == 31)
                *opc = dot;  // raw; silu in epilogue
            opc += BATCH * NDIM;
        }
    }

    // peeled final outer iteration: t = 508..511, prefetch clamped
#pragma unroll
    for (int j = 0; j < 4; ++j) {
        const int ps = (j + 2) & 3;
        int tp = 510 + j;
        if (tp > T_STEPS - 1) tp = T_STEPS - 1;
        const float* p = pb + (size_t)tp * STRIDE;
        kS[ps]  = *(const f32x4*)(p + col0);
        qS[ps]  = *(const f32x4*)(p + 2 * NDIM + col0);
        eS[ps]  = p[3 * NDIM + row];
        wvS[ps] = p[NDIM + row];

        float dot = 0.0f;
#pragma unroll
        for (int u = 0; u < 4; ++u) {
            float t0  = fmaf(-eS[j], S[u], wvS[j]);
            float pre = fmaf(kS[j][u], t0, S[u]);
            S[u] = tanh_fast(pre);
            dot = fmaf(S[u], qS[j][u], dot);
        }
        dot = dpp_reduce32(dot);

        if ((threadIdx.x & 31) == 31)
            *opc = dot;
        opc += BATCH * NDIM;
    }

    *(f32x4*)(out + (size_t)T_STEPS * BATCH * NDIM
              + ((size_t)b * NDIM + row) * NDIM + col0) = S;
}

// ---------------- silu epilogue: y = d^2 * sigmoid(d) over out[0:OUT_N] ----
__global__ __launch_bounds__(256) void silu_kernel(float* __restrict__ out)
{
    const int i = blockIdx.x * 256 + threadIdx.x;  // f32x4 index
    f32x4 d = ((const f32x4*)out)[i];
    f32x4 y;
#pragma unroll
    for (int j = 0; j < 4; ++j) {
        float sg = __builtin_amdgcn_rcpf(
            1.0f + __builtin_amdgcn_exp2f(-d[j] * 1.4426950408889634f));
        y[j] = d[j] * d[j] * sg;
    }
    ((f32x4*)out)[i] = y;
}

extern "C" void kernel_launch(void* const* d_in, const int* in_sizes, int n_in,
                              void* d_out, int out_size, void* d_ws, size_t ws_size,
                              hipStream_t stream) {
    const float* x  = (const float*)d_in[0];
    const float* S0 = (const float*)d_in[1];
    const float* wk = (const float*)d_in[2];
    const float* wv = (const float*)d_in[3];
    const float* wq = (const float*)d_in[4];
    const float* we = (const float*)d_in[5];
    const float* ww = (const float*)d_in[6];
    float* out = (float*)d_out;
    float* C   = (float*)d_ws;
    unsigned short* W2 = (unsigned short*)((char*)d_ws + C_BYTES);

    wconv_kernel<<<640, 256, 0, stream>>>(wk, wv, wq, we, ww, W2);
    gemm8_kernel<<<256, 512, 0, stream>>>(x, W2, C);
    knorm_kernel<<<MROWS / 4, 256, 0, stream>>>(C);
    ntm_scan_kernel<<<512, 256, 0, stream>>>(C, S0, out);
    silu_kernel<<<OUT_N / 1024, 256, 0, stream>>>(out);
}